// Round 8
// baseline (114.714 us; speedup 1.0000x reference)
//
#include <hip/hip_runtime.h>

#define N_VERT 50000
#define KNBR 20
#define F 128
#define NBLK 782   // ceil(50000/64)

typedef unsigned int uint32;
typedef unsigned short ushort16;
typedef unsigned char uint8;
typedef __attribute__((ext_vector_type(8))) short bf16x8;
typedef __attribute__((ext_vector_type(4))) float f32x4;

__device__ __forceinline__ uint32 f2bf_bits(float x) {
    uint32 u = __float_as_uint(x);
    u += 0x7fff + ((u >> 16) & 1);        // round-to-nearest-even
    return u >> 16;
}

// ---------------------------------------------------------------------------
// Kernel W: weights -> bf16 fragment-linear Wt (as R6/R7) + permuted bias.
// Permuted column order everywhere: c' = lr*8 + nt  <->  filter nt*16 + lr.
// ---------------------------------------------------------------------------
__global__ __launch_bounds__(256) void wconv_kernel(
    const float* __restrict__ Wc, const float* __restrict__ Wi,
    const float* __restrict__ Wn, const float* __restrict__ bv,
    ushort16* __restrict__ Wt, float* __restrict__ bvp)
{
    int t = blockIdx.x * 256 + threadIdx.x;
    if (blockIdx.x == 0 && threadIdx.x < 128) {
        int c = threadIdx.x;                    // c' = lr*8+nt
        bvp[c] = bv[(c & 7) * 16 + (c >> 3)];   // filter nt*16+lr
    }
    if (t >= 3 * F * F) return;
    int w    = t >> 14;
    int r    = t & 16383;
    int kk   = r >> 12;
    int r2   = r & 4095;
    int nt   = r2 >> 9;
    int r3   = r2 & 511;
    int lane = r3 >> 3;
    int e    = r3 & 7;
    int k = kk * 32 + (lane >> 4) * 8 + e;
    int n = nt * 16 + (lane & 15);
    const float* W = (w == 0) ? Wc : ((w == 1) ? Wi : Wn);
    Wt[t] = (ushort16)f2bf_bits(W[k * F + n]);
}

// ---------------------------------------------------------------------------
// Kernel A: projections via bf16 MFMA, w-split grid (blockIdx.y = which W).
// acc = 8 f32x4 (32 VGPR persistent), NO LDS: outputs stored straight from
// D-fragments in permuted column order c' = lr*8 + nt (contiguous per lane).
//   w==0 -> zcp bf16[N][128]   (8 ushorts = 16 B per row-store)
//   w==1/2 -> pay int8[N][128] + per-row scale (shfl row-absmax, no LDS)
// ---------------------------------------------------------------------------
__global__ __launch_bounds__(256) void mfma_proj_kernel(
    const float*    __restrict__ vert,
    const ushort16* __restrict__ Wt,
    ushort16* __restrict__ zcp,
    uint8* __restrict__ pay_i, float* __restrict__ sc_i,
    uint8* __restrict__ pay_n, float* __restrict__ sc_n)
{
    const int w    = blockIdx.y;
    const int wave = threadIdx.x >> 6;
    const int lane = threadIdx.x & 63;
    const int lr   = lane & 15;
    const int lk   = lane >> 4;
    const int rb   = (blockIdx.x * 4 + wave) * 16;

    // A fragments (V rows read once, converted inline; clamped tail)
    int rowA = rb + lr; if (rowA > N_VERT - 1) rowA = N_VERT - 1;
    const float* vrow = vert + (size_t)rowA * F;
    bf16x8 afrag[4];
#pragma unroll
    for (int kk = 0; kk < 4; ++kk) {
        const float* p = vrow + kk * 32 + lk * 8;
        f32x4 lo = *(const f32x4*)p;
        f32x4 hi = *(const f32x4*)(p + 4);
#pragma unroll
        for (int j = 0; j < 4; ++j) {
            afrag[kk][j]     = (short)f2bf_bits(lo[j]);
            afrag[kk][4 + j] = (short)f2bf_bits(hi[j]);
        }
    }

    f32x4 acc[8];
#pragma unroll
    for (int nt = 0; nt < 8; ++nt) acc[nt] = (f32x4)(0.f);

#pragma unroll
    for (int kk = 0; kk < 4; ++kk)
#pragma unroll
        for (int nt = 0; nt < 8; ++nt) {
            bf16x8 b = *(const bf16x8*)(
                Wt + ((size_t)((w * 4 + kk) * 8 + nt)) * 512 + lane * 8);
            acc[nt] = __builtin_amdgcn_mfma_f32_16x16x32_bf16(
                afrag[kk], b, acc[nt], 0, 0, 0);
        }

    if (w == 0) {
        // ---- zc as bf16, permuted: lane stores 8 ushorts per row ----
#pragma unroll
        for (int j = 0; j < 4; ++j) {
            int row = rb + lk * 4 + j;
            uint32 d[4];
#pragma unroll
            for (int p = 0; p < 4; ++p)
                d[p] = f2bf_bits(acc[2 * p][j]) | (f2bf_bits(acc[2 * p + 1][j]) << 16);
            if (row < N_VERT)
                *(uint4*)((uint8*)zcp + (size_t)row * 256 + lr * 16) =
                    make_uint4(d[0], d[1], d[2], d[3]);
        }
    } else {
        uint8* pay = (w == 1) ? pay_i : pay_n;
        float* sc  = (w == 1) ? sc_i : sc_n;
        // row absmax via shfl over the 16 lr-lanes (xor masks stay in-group)
        float m0 = 0.f, m1 = 0.f, m2 = 0.f, m3 = 0.f;
#pragma unroll
        for (int nt = 0; nt < 8; ++nt) {
            m0 = fmaxf(m0, fabsf(acc[nt][0]));
            m1 = fmaxf(m1, fabsf(acc[nt][1]));
            m2 = fmaxf(m2, fabsf(acc[nt][2]));
            m3 = fmaxf(m3, fabsf(acc[nt][3]));
        }
#pragma unroll
        for (int s = 1; s < 16; s <<= 1) {
            m0 = fmaxf(m0, __shfl_xor(m0, s));
            m1 = fmaxf(m1, __shfl_xor(m1, s));
            m2 = fmaxf(m2, __shfl_xor(m2, s));
            m3 = fmaxf(m3, __shfl_xor(m3, s));
        }
        float mj[4] = {m0, m1, m2, m3};
#pragma unroll
        for (int j = 0; j < 4; ++j) {
            int row = rb + lk * 4 + j;
            float inv = (mj[j] > 0.f) ? 127.f / mj[j] : 0.f;
            uint32 lo = 0, hi = 0;
#pragma unroll
            for (int nt = 0; nt < 4; ++nt) {
                int q0 = (int)rintf(acc[nt][j] * inv);
                int q1 = (int)rintf(acc[nt + 4][j] * inv);
                lo |= ((uint32)(q0 & 255)) << (8 * nt);
                hi |= ((uint32)(q1 & 255)) << (8 * nt);
            }
            if (row < N_VERT)
                *(uint2*)(pay + (size_t)row * 128 + lr * 8) = make_uint2(lo, hi);
        }
        // one lane per row writes the scale
        float s_sel = (lr == 0) ? m0 : (lr == 1) ? m1 : (lr == 2) ? m2 : m3;
        if (lr < 4) {
            int row = rb + lk * 4 + lr;
            if (row < N_VERT) sc[row] = s_sel * (1.f / 127.f);
        }
    }
}

// ---------------------------------------------------------------------------
// Kernel B: gather-aggregate on permuted int8 payload + permuted bf16 zc.
// Gather addresses identical to R7; byte t of lane fg means filter t*16+fg.
// Final z un-permuted through a small per-wave LDS stage (stride 136, 2-way).
// ---------------------------------------------------------------------------
__global__ __launch_bounds__(256) void agg_kernel(
    const uint8*  __restrict__ pay_i, const float* __restrict__ sc_i,
    const uint8*  __restrict__ pay_n, const float* __restrict__ sc_n,
    const unsigned short* __restrict__ zcp,
    const float*  __restrict__ bvp,
    const int4*   __restrict__ int_idx4,
    const int4*   __restrict__ nh_idx4,
    const float4* __restrict__ int_e4,
    const float4* __restrict__ nh_e4,
    float* __restrict__ z)
{
    __shared__ float zs_all[4][4 * 136];

    const int lane = threadIdx.x & 63;
    const int wave = threadIdx.x >> 6;
    const int vg   = lane >> 4;
    const int fg   = lane & 15;
    const int i    = blockIdx.x * 16 + wave * 4 + vg;

    float a_i[8], a_n[8];
#pragma unroll
    for (int j = 0; j < 8; ++j) { a_i[j] = 0.f; a_n[j] = 0.f; }
    int ci = 0, cn = 0;

    // ---------------- interface edges ----------------
    {
        int sidx[KNBR]; float f[KNBR];
#pragma unroll
        for (int q = 0; q < 5; ++q) {
            int4   a = int_idx4[i * 5 + q];
            float4 e = int_e4[i * 5 + q];
            int   av[4] = {a.x, a.y, a.z, a.w};
            float ev[4] = {e.x, e.y, e.z, e.w};
#pragma unroll
            for (int j = 0; j < 4; ++j) {
                bool v = av[j] >= 0;
                ci += v;
                sidx[4 * q + j] = v ? av[j] : 0;
                f[4 * q + j]    = v ? ev[j] : 0.f;
            }
        }
#pragma unroll
        for (int k = 0; k < KNBR; ++k) f[k] *= sc_i[sidx[k]];
        uint2 g[KNBR];
#pragma unroll
        for (int k = 0; k < KNBR; ++k)
            g[k] = *(const uint2*)(pay_i + (size_t)sidx[k] * 128 + fg * 8);
#pragma unroll
        for (int k = 0; k < KNBR; ++k) {
            float e = f[k];
            uint32 d0 = g[k].x, d1 = g[k].y;
#pragma unroll
            for (int b = 0; b < 4; ++b) {
                a_i[b]     = fmaf((float)((int)(d0 << (24 - 8 * b)) >> 24), e, a_i[b]);
                a_i[4 + b] = fmaf((float)((int)(d1 << (24 - 8 * b)) >> 24), e, a_i[4 + b]);
            }
        }
    }
    // ---------------- neighborhood edges ----------------
    {
        int sidx[KNBR]; float f[KNBR];
#pragma unroll
        for (int q = 0; q < 5; ++q) {
            int4   a = nh_idx4[i * 5 + q];
            float4 e = nh_e4[i * 5 + q];
            int   av[4] = {a.x, a.y, a.z, a.w};
            float ev[4] = {e.x, e.y, e.z, e.w};
#pragma unroll
            for (int j = 0; j < 4; ++j) {
                bool v = av[j] >= 0;
                cn += v;
                sidx[4 * q + j] = v ? av[j] : 0;
                f[4 * q + j]    = v ? ev[j] : 0.f;
            }
        }
#pragma unroll
        for (int k = 0; k < KNBR; ++k) f[k] *= sc_n[sidx[k]];
        uint2 g[KNBR];
#pragma unroll
        for (int k = 0; k < KNBR; ++k)
            g[k] = *(const uint2*)(pay_n + (size_t)sidx[k] * 128 + fg * 8);
#pragma unroll
        for (int k = 0; k < KNBR; ++k) {
            float e = f[k];
            uint32 d0 = g[k].x, d1 = g[k].y;
#pragma unroll
            for (int b = 0; b < 4; ++b) {
                a_n[b]     = fmaf((float)((int)(d0 << (24 - 8 * b)) >> 24), e, a_n[b]);
                a_n[4 + b] = fmaf((float)((int)(d1 << (24 - 8 * b)) >> 24), e, a_n[4 + b]);
            }
        }
    }

    float ri = 1.f / (float)max(ci, 1);
    float rn = 1.f / (float)max(cn, 1);

    // own-row Zc (bf16, permuted, coalesced 16 B/lane) + permuted bias
    uint4 zq = *(const uint4*)(zcp + (size_t)i * 128 + fg * 8);
    f32x4 b0 = *(const f32x4*)(bvp + fg * 8);
    f32x4 b1 = *(const f32x4*)(bvp + fg * 8 + 4);
    uint32 zd[4] = {zq.x, zq.y, zq.z, zq.w};

    float* zs = zs_all[wave] + vg * 136;
#pragma unroll
    for (int t = 0; t < 8; ++t) {
        uint32 dw = zd[t >> 1];
        float zc = __uint_as_float((t & 1) ? (dw & 0xffff0000u) : (dw << 16));
        float bb = (t < 4) ? b0[t] : b1[t - 4];
        float r  = zc + a_i[t] * ri + a_n[t] * rn + bb;
        zs[t * 16 + fg] = fmaxf(r, 0.f);   // filter t*16+fg
    }

    // un-permute: coalesced write of this wave's 4 vertices
    const float* src = zs_all[wave] + (lane >> 4) * 136 + (lane & 15) * 8;
    f32x4 o0 = *(const f32x4*)src;
    f32x4 o1 = *(const f32x4*)(src + 4);
    int iv = blockIdx.x * 16 + wave * 4 + (lane >> 4);
    float* dst = z + (size_t)iv * F + (lane & 15) * 8;
    *(f32x4*)dst       = o0;
    *(f32x4*)(dst + 4) = o1;
}

// ---------------------------------------------------------------------------
// Kernel C: passthrough outputs 1..5, written as float32 VALUES.
// ---------------------------------------------------------------------------
__global__ void pass_kernel(const int*   __restrict__ nh_idx,
                            const int*   __restrict__ int_idx,
                            const float* __restrict__ nh_e,
                            const float* __restrict__ int_e,
                            const int*   __restrict__ is_int,
                            float* __restrict__ out)
{
    const size_t NK    = (size_t)N_VERT * KNBR;
    const size_t total = 4 * NK + N_VERT;
    size_t t = (size_t)blockIdx.x * blockDim.x + threadIdx.x;
    if (t >= total) return;

    float v;
    if      (t <     NK) v = (float)nh_idx[t];
    else if (t < 2 * NK) v = (float)int_idx[t - NK];
    else if (t < 3 * NK) v = nh_e[t - 2 * NK];
    else if (t < 4 * NK) v = int_e[t - 3 * NK];
    else                 v = (float)is_int[t - 4 * NK];
    out[t] = v;
}

extern "C" void kernel_launch(void* const* d_in, const int* in_sizes, int n_in,
                              void* d_out, int out_size, void* d_ws, size_t ws_size,
                              hipStream_t stream) {
    const float* vert    = (const float*)d_in[0];
    const int*   nh_idx  = (const int*)  d_in[1];
    const int*   int_idx = (const int*)  d_in[2];
    const float* nh_e    = (const float*)d_in[3];
    const float* int_e   = (const float*)d_in[4];
    const int*   is_int  = (const int*)  d_in[5];
    const float* Wc      = (const float*)d_in[6];
    const float* Wi      = (const float*)d_in[7];
    const float* Wn      = (const float*)d_in[8];
    const float* bv      = (const float*)d_in[9];

    float* z        = (float*)d_out;                     // [N, F]
    float* out_rest = z + (size_t)N_VERT * F;            // passthrough chunks

    uint8* pay_i = (uint8*)d_ws;                         // int8 [N][128] permuted
    uint8* pay_n = pay_i + (size_t)N_VERT * F;           // int8 [N][128] permuted
    float* sc_i  = (float*)(pay_n + (size_t)N_VERT * F); // f32 [N]
    float* sc_n  = sc_i + N_VERT;                        // f32 [N]
    ushort16* zcp = (ushort16*)(sc_n + N_VERT);          // bf16 [N][128] permuted
    float* bvp   = (float*)(zcp + (size_t)N_VERT * F);   // f32 [128] permuted
    ushort16* Wt = (ushort16*)(bvp + F);                 // bf16 fragment-linear

    wconv_kernel<<<(3 * F * F + 255) / 256, 256, 0, stream>>>(Wc, Wi, Wn, bv, Wt, bvp);
    mfma_proj_kernel<<<dim3(NBLK, 3), 256, 0, stream>>>(
        vert, Wt, zcp, pay_i, sc_i, pay_n, sc_n);
    agg_kernel<<<N_VERT / 16, 256, 0, stream>>>(
        pay_i, sc_i, pay_n, sc_n, (const unsigned short*)zcp, bvp,
        (const int4*)int_idx, (const int4*)nh_idx,
        (const float4*)int_e, (const float4*)nh_e, z);

    const size_t total = (size_t)4 * N_VERT * KNBR + N_VERT;
    pass_kernel<<<(int)((total + 255) / 256), 256, 0, stream>>>(
        nh_idx, int_idx, nh_e, int_e, is_int, out_rest);
}

// Round 9
// 82.917 us; speedup vs baseline: 1.3835x; 1.3835x over previous
//
#include <hip/hip_runtime.h>

#define N_VERT 50000
#define KNBR 20
#define F 128
#define NBLK 782   // ceil(50000/64)

typedef unsigned int uint32;
typedef unsigned short ushort16;
typedef unsigned char uint8;
typedef __attribute__((ext_vector_type(8))) short bf16x8;
typedef __attribute__((ext_vector_type(4))) float f32x4;

__device__ __forceinline__ uint32 f2bf_bits(float x) {
    uint32 u = __float_as_uint(x);
    u += 0x7fff + ((u >> 16) & 1);        // round-to-nearest-even
    return u >> 16;
}

// ---------------------------------------------------------------------------
// Kernel W: weights -> bf16 fragment-linear Wt + permuted bias bvp.
// Permuted column order: c' = lr*8 + nt  <->  filter nt*16 + lr.
// ---------------------------------------------------------------------------
__global__ __launch_bounds__(256) void wconv_kernel(
    const float* __restrict__ Wc, const float* __restrict__ Wi,
    const float* __restrict__ Wn, const float* __restrict__ bv,
    ushort16* __restrict__ Wt, float* __restrict__ bvp)
{
    int t = blockIdx.x * 256 + threadIdx.x;
    if (blockIdx.x == 0 && threadIdx.x < 128) {
        int c = threadIdx.x;                    // c' = lr*8+nt
        bvp[c] = bv[(c & 7) * 16 + (c >> 3)];   // filter nt*16+lr
    }
    if (t >= 3 * F * F) return;
    int w    = t >> 14;
    int r    = t & 16383;
    int kk   = r >> 12;
    int r2   = r & 4095;
    int nt   = r2 >> 9;
    int r3   = r2 & 511;
    int lane = r3 >> 3;
    int e    = r3 & 7;
    int k = kk * 32 + (lane >> 4) * 8 + e;
    int n = nt * 16 + (lane & 15);
    const float* W = (w == 0) ? Wc : ((w == 1) ? Wi : Wn);
    Wt[t] = (ushort16)f2bf_bits(W[k * F + n]);
}

// ---------------------------------------------------------------------------
// Kernel A: projections via bf16 MFMA, w-split grid (blockIdx.y = which W).
// All outputs stored register-direct in permuted column order c' = lr*8+nt.
//   w==0 -> zcp bf16[N][128]  with BIAS PRE-ADDED (removes bv from agg)
//   w==1/2 -> pay int8[N][128] + per-row scale (shfl row-absmax, no LDS)
// ---------------------------------------------------------------------------
__global__ __launch_bounds__(256) void mfma_proj_kernel(
    const float*    __restrict__ vert,
    const ushort16* __restrict__ Wt,
    const float*    __restrict__ bvp,
    ushort16* __restrict__ zcp,
    uint8* __restrict__ pay_i, float* __restrict__ sc_i,
    uint8* __restrict__ pay_n, float* __restrict__ sc_n)
{
    const int w    = blockIdx.y;
    const int wave = threadIdx.x >> 6;
    const int lane = threadIdx.x & 63;
    const int lr   = lane & 15;
    const int lk   = lane >> 4;
    const int rb   = (blockIdx.x * 4 + wave) * 16;

    int rowA = rb + lr; if (rowA > N_VERT - 1) rowA = N_VERT - 1;
    const float* vrow = vert + (size_t)rowA * F;
    bf16x8 afrag[4];
#pragma unroll
    for (int kk = 0; kk < 4; ++kk) {
        const float* p = vrow + kk * 32 + lk * 8;
        f32x4 lo = *(const f32x4*)p;
        f32x4 hi = *(const f32x4*)(p + 4);
#pragma unroll
        for (int j = 0; j < 4; ++j) {
            afrag[kk][j]     = (short)f2bf_bits(lo[j]);
            afrag[kk][4 + j] = (short)f2bf_bits(hi[j]);
        }
    }

    f32x4 acc[8];
#pragma unroll
    for (int nt = 0; nt < 8; ++nt) acc[nt] = (f32x4)(0.f);

#pragma unroll
    for (int kk = 0; kk < 4; ++kk)
#pragma unroll
        for (int nt = 0; nt < 8; ++nt) {
            bf16x8 b = *(const bf16x8*)(
                Wt + ((size_t)((w * 4 + kk) * 8 + nt)) * 512 + lane * 8);
            acc[nt] = __builtin_amdgcn_mfma_f32_16x16x32_bf16(
                afrag[kk], b, acc[nt], 0, 0, 0);
        }

    if (w == 0) {
        // bias pre-add (filter nt*16+lr -> bvp[lr*8+nt]), then bf16 permuted store
        f32x4 bb0 = *(const f32x4*)(bvp + lr * 8);
        f32x4 bb1 = *(const f32x4*)(bvp + lr * 8 + 4);
        float bbv[8] = {bb0[0], bb0[1], bb0[2], bb0[3], bb1[0], bb1[1], bb1[2], bb1[3]};
#pragma unroll
        for (int j = 0; j < 4; ++j) {
            int row = rb + lk * 4 + j;
            uint32 d[4];
#pragma unroll
            for (int p = 0; p < 4; ++p)
                d[p] = f2bf_bits(acc[2 * p][j] + bbv[2 * p]) |
                       (f2bf_bits(acc[2 * p + 1][j] + bbv[2 * p + 1]) << 16);
            if (row < N_VERT)
                *(uint4*)((uint8*)zcp + (size_t)row * 256 + lr * 16) =
                    make_uint4(d[0], d[1], d[2], d[3]);
        }
    } else {
        uint8* pay = (w == 1) ? pay_i : pay_n;
        float* sc  = (w == 1) ? sc_i : sc_n;
        float m0 = 0.f, m1 = 0.f, m2 = 0.f, m3 = 0.f;
#pragma unroll
        for (int nt = 0; nt < 8; ++nt) {
            m0 = fmaxf(m0, fabsf(acc[nt][0]));
            m1 = fmaxf(m1, fabsf(acc[nt][1]));
            m2 = fmaxf(m2, fabsf(acc[nt][2]));
            m3 = fmaxf(m3, fabsf(acc[nt][3]));
        }
#pragma unroll
        for (int s = 1; s < 16; s <<= 1) {
            m0 = fmaxf(m0, __shfl_xor(m0, s));
            m1 = fmaxf(m1, __shfl_xor(m1, s));
            m2 = fmaxf(m2, __shfl_xor(m2, s));
            m3 = fmaxf(m3, __shfl_xor(m3, s));
        }
        float mj[4] = {m0, m1, m2, m3};
#pragma unroll
        for (int j = 0; j < 4; ++j) {
            int row = rb + lk * 4 + j;
            float inv = (mj[j] > 0.f) ? 127.f / mj[j] : 0.f;
            uint32 lo = 0, hi = 0;
#pragma unroll
            for (int nt = 0; nt < 4; ++nt) {
                int q0 = (int)rintf(acc[nt][j] * inv);
                int q1 = (int)rintf(acc[nt + 4][j] * inv);
                lo |= ((uint32)(q0 & 255)) << (8 * nt);
                hi |= ((uint32)(q1 & 255)) << (8 * nt);
            }
            if (row < N_VERT)
                *(uint2*)(pay + (size_t)row * 128 + lr * 8) = make_uint2(lo, hi);
        }
        float s_sel = (lr == 0) ? m0 : (lr == 1) ? m1 : (lr == 2) ? m2 : m3;
        if (lr < 4) {
            int row = rb + lk * 4 + lr;
            if (row < N_VERT) sc[row] = s_sel * (1.f / 127.f);
        }
    }
}

// ---------------------------------------------------------------------------
// Kernel B: gather-aggregate on permuted int8 payload (R7's proven body).
// Epilogue is register-free: zcp row (bias pre-added) + 8 scattered dword
// stores un-permute directly to z. No LDS, no bias read; target VGPR <= 64.
// ---------------------------------------------------------------------------
__global__ __launch_bounds__(256) void agg_kernel(
    const uint8*  __restrict__ pay_i, const float* __restrict__ sc_i,
    const uint8*  __restrict__ pay_n, const float* __restrict__ sc_n,
    const unsigned short* __restrict__ zcp,
    const int4*   __restrict__ int_idx4,
    const int4*   __restrict__ nh_idx4,
    const float4* __restrict__ int_e4,
    const float4* __restrict__ nh_e4,
    float* __restrict__ z)
{
    const int lane = threadIdx.x & 63;
    const int wave = threadIdx.x >> 6;
    const int vg   = lane >> 4;
    const int fg   = lane & 15;
    const int i    = blockIdx.x * 16 + wave * 4 + vg;

    float a_i[8], a_n[8];
#pragma unroll
    for (int j = 0; j < 8; ++j) { a_i[j] = 0.f; a_n[j] = 0.f; }
    int ci = 0, cn = 0;

    // ---------------- interface edges ----------------
    {
        int sidx[KNBR]; float f[KNBR];
#pragma unroll
        for (int q = 0; q < 5; ++q) {
            int4   a = int_idx4[i * 5 + q];
            float4 e = int_e4[i * 5 + q];
            int   av[4] = {a.x, a.y, a.z, a.w};
            float ev[4] = {e.x, e.y, e.z, e.w};
#pragma unroll
            for (int j = 0; j < 4; ++j) {
                bool v = av[j] >= 0;
                ci += v;
                sidx[4 * q + j] = v ? av[j] : 0;
                f[4 * q + j]    = v ? ev[j] : 0.f;
            }
        }
#pragma unroll
        for (int k = 0; k < KNBR; ++k) f[k] *= sc_i[sidx[k]];
        uint2 g[KNBR];
#pragma unroll
        for (int k = 0; k < KNBR; ++k)
            g[k] = *(const uint2*)(pay_i + (size_t)sidx[k] * 128 + fg * 8);
#pragma unroll
        for (int k = 0; k < KNBR; ++k) {
            float e = f[k];
            uint32 d0 = g[k].x, d1 = g[k].y;
#pragma unroll
            for (int b = 0; b < 4; ++b) {
                a_i[b]     = fmaf((float)((int)(d0 << (24 - 8 * b)) >> 24), e, a_i[b]);
                a_i[4 + b] = fmaf((float)((int)(d1 << (24 - 8 * b)) >> 24), e, a_i[4 + b]);
            }
        }
    }
    // ---------------- neighborhood edges ----------------
    {
        int sidx[KNBR]; float f[KNBR];
#pragma unroll
        for (int q = 0; q < 5; ++q) {
            int4   a = nh_idx4[i * 5 + q];
            float4 e = nh_e4[i * 5 + q];
            int   av[4] = {a.x, a.y, a.z, a.w};
            float ev[4] = {e.x, e.y, e.z, e.w};
#pragma unroll
            for (int j = 0; j < 4; ++j) {
                bool v = av[j] >= 0;
                cn += v;
                sidx[4 * q + j] = v ? av[j] : 0;
                f[4 * q + j]    = v ? ev[j] : 0.f;
            }
        }
#pragma unroll
        for (int k = 0; k < KNBR; ++k) f[k] *= sc_n[sidx[k]];
        uint2 g[KNBR];
#pragma unroll
        for (int k = 0; k < KNBR; ++k)
            g[k] = *(const uint2*)(pay_n + (size_t)sidx[k] * 128 + fg * 8);
#pragma unroll
        for (int k = 0; k < KNBR; ++k) {
            float e = f[k];
            uint32 d0 = g[k].x, d1 = g[k].y;
#pragma unroll
            for (int b = 0; b < 4; ++b) {
                a_n[b]     = fmaf((float)((int)(d0 << (24 - 8 * b)) >> 24), e, a_n[b]);
                a_n[4 + b] = fmaf((float)((int)(d1 << (24 - 8 * b)) >> 24), e, a_n[4 + b]);
            }
        }
    }

    float ri = 1.f / (float)max(ci, 1);
    float rn = 1.f / (float)max(cn, 1);

    // zcp row: bf16 permuted, bias pre-added; un-permute via 8 dword stores
    uint4 zq = *(const uint4*)(zcp + (size_t)i * 128 + fg * 8);
    uint32 zd[4] = {zq.x, zq.y, zq.z, zq.w};
    float* zrow = z + (size_t)i * F + fg;
#pragma unroll
    for (int t = 0; t < 8; ++t) {
        uint32 dw = zd[t >> 1];
        float zc = __uint_as_float((t & 1) ? (dw & 0xffff0000u) : (dw << 16));
        float r  = zc + a_i[t] * ri + a_n[t] * rn;
        zrow[t * 16] = fmaxf(r, 0.f);      // filter t*16+fg
    }
}

// ---------------------------------------------------------------------------
// Kernel C: passthrough outputs 1..5, written as float32 VALUES.
// ---------------------------------------------------------------------------
__global__ void pass_kernel(const int*   __restrict__ nh_idx,
                            const int*   __restrict__ int_idx,
                            const float* __restrict__ nh_e,
                            const float* __restrict__ int_e,
                            const int*   __restrict__ is_int,
                            float* __restrict__ out)
{
    const size_t NK    = (size_t)N_VERT * KNBR;
    const size_t total = 4 * NK + N_VERT;
    size_t t = (size_t)blockIdx.x * blockDim.x + threadIdx.x;
    if (t >= total) return;

    float v;
    if      (t <     NK) v = (float)nh_idx[t];
    else if (t < 2 * NK) v = (float)int_idx[t - NK];
    else if (t < 3 * NK) v = nh_e[t - 2 * NK];
    else if (t < 4 * NK) v = int_e[t - 3 * NK];
    else                 v = (float)is_int[t - 4 * NK];
    out[t] = v;
}

extern "C" void kernel_launch(void* const* d_in, const int* in_sizes, int n_in,
                              void* d_out, int out_size, void* d_ws, size_t ws_size,
                              hipStream_t stream) {
    const float* vert    = (const float*)d_in[0];
    const int*   nh_idx  = (const int*)  d_in[1];
    const int*   int_idx = (const int*)  d_in[2];
    const float* nh_e    = (const float*)d_in[3];
    const float* int_e   = (const float*)d_in[4];
    const int*   is_int  = (const int*)  d_in[5];
    const float* Wc      = (const float*)d_in[6];
    const float* Wi      = (const float*)d_in[7];
    const float* Wn      = (const float*)d_in[8];
    const float* bv      = (const float*)d_in[9];

    float* z        = (float*)d_out;                     // [N, F]
    float* out_rest = z + (size_t)N_VERT * F;            // passthrough chunks

    uint8* pay_i = (uint8*)d_ws;                         // int8 [N][128] permuted
    uint8* pay_n = pay_i + (size_t)N_VERT * F;           // int8 [N][128] permuted
    float* sc_i  = (float*)(pay_n + (size_t)N_VERT * F); // f32 [N]
    float* sc_n  = sc_i + N_VERT;                        // f32 [N]
    ushort16* zcp = (ushort16*)(sc_n + N_VERT);          // bf16 [N][128] permuted (+bias)
    float* bvp   = (float*)(zcp + (size_t)N_VERT * F);   // f32 [128] permuted
    ushort16* Wt = (ushort16*)(bvp + F);                 // bf16 fragment-linear

    wconv_kernel<<<(3 * F * F + 255) / 256, 256, 0, stream>>>(Wc, Wi, Wn, bv, Wt, bvp);
    mfma_proj_kernel<<<dim3(NBLK, 3), 256, 0, stream>>>(
        vert, Wt, bvp, zcp, pay_i, sc_i, pay_n, sc_n);
    agg_kernel<<<N_VERT / 16, 256, 0, stream>>>(
        pay_i, sc_i, pay_n, sc_n, (const unsigned short*)zcp,
        (const int4*)int_idx, (const int4*)nh_idx,
        (const float4*)int_e, (const float4*)nh_e, z);

    const size_t total = (size_t)4 * N_VERT * KNBR + N_VERT;
    pass_kernel<<<(int)((total + 255) / 256), 256, 0, stream>>>(
        nh_idx, int_idx, nh_e, int_e, is_int, out_rest);
}